// Round 1
// 703.843 us; speedup vs baseline: 1.0264x; 1.0264x over previous
//
#include <hip/hip_runtime.h>

#define N_NODES 50000
#define N_EDGES 800000
#define F_INP   32
#define HDIM    64
#define EDIM    16
#define COUT    40
#define NGRAPH  64

// ---------------------------------------------------------------- sort by dst
__global__ void hist_kernel(const int* __restrict__ dst, int* __restrict__ cnt, int E) {
    int e = blockIdx.x * 256 + threadIdx.x;
    if (e < E) atomicAdd(&cnt[dst[e]], 1);
}

// 3-stage scan: block partial sums -> 1-block scan of sums -> apply
__global__ void scan_part_kernel(const int* __restrict__ cnt, int* __restrict__ bsum, int n) {
    __shared__ int red[256];
    int tid = threadIdx.x;
    int idx = blockIdx.x * 256 + tid;
    red[tid] = (idx < n) ? cnt[idx] : 0;
    __syncthreads();
    for (int off = 128; off > 0; off >>= 1) {
        if (tid < off) red[tid] += red[tid + off];
        __syncthreads();
    }
    if (tid == 0) bsum[blockIdx.x] = red[0];
}

__global__ void scan_top_kernel(int* __restrict__ bsum, int nb) {
    __shared__ int tmp[256];
    int tid = threadIdx.x;
    int v = (tid < nb) ? bsum[tid] : 0;
    tmp[tid] = v;
    __syncthreads();
    for (int off = 1; off < 256; off <<= 1) {
        int x = (tid >= off) ? tmp[tid - off] : 0;
        __syncthreads();
        tmp[tid] += x;
        __syncthreads();
    }
    if (tid < nb) bsum[tid] = tmp[tid] - v;   // exclusive
}

__global__ void scan_apply_kernel(const int* __restrict__ cnt, const int* __restrict__ bsum,
                                  int* __restrict__ offsets, int* __restrict__ cursor, int n) {
    __shared__ int tmp[256];
    int tid = threadIdx.x;
    int idx = blockIdx.x * 256 + tid;
    int v = (idx < n) ? cnt[idx] : 0;
    tmp[tid] = v;
    __syncthreads();
    for (int off = 1; off < 256; off <<= 1) {
        int x = (tid >= off) ? tmp[tid - off] : 0;
        __syncthreads();
        tmp[tid] += x;
        __syncthreads();
    }
    int excl = tmp[tid] - v + bsum[blockIdx.x];
    if (idx < n) { offsets[idx] = excl; cursor[idx] = excl; }
    if (idx == n - 1) offsets[n] = excl + v;
}

__global__ void scatter_kernel(const int* __restrict__ dst, int* __restrict__ cursor,
                               int* __restrict__ sorted, int E) {
    int e = blockIdx.x * 256 + threadIdx.x;
    if (e < E) {
        int p = atomicAdd(&cursor[dst[e]], 1);
        sorted[p] = e;
    }
}

// batch is sorted ascending; find graph start offsets
__global__ void gstart_kernel(const int* __restrict__ batch, int* __restrict__ gstart,
                              int N, int G) {
    int n = blockIdx.x * 256 + threadIdx.x;
    if (n >= N) return;
    int g  = batch[n];
    int gp = (n == 0) ? -1 : batch[n - 1];
    for (int gg = gp + 1; gg <= g; gg++) gstart[gg] = n;
    if (n == N - 1) {
        for (int gg = g + 1; gg <= G; gg++) gstart[gg] = N;
    }
}

// ---------------------------------------------------------------- input linear
// h[n][c] = b[c] + sum_k x[n][k] * W[k][c]   (N,32)@(32,64); W column in regs
__global__ void lin_in_kernel(const float* __restrict__ x, const float* __restrict__ W,
                              const float* __restrict__ b, float* __restrict__ h, int N) {
    int tid = threadIdx.x;
    int c = tid & 63;
    float w[F_INP];
#pragma unroll
    for (int k = 0; k < F_INP; k++) w[k] = W[k * HDIM + c];
    int node = blockIdx.x * 4 + (tid >> 6);
    if (node >= N) return;
    const float4* xr = (const float4*)(x + (size_t)node * F_INP);
    float acc = b[c];
#pragma unroll
    for (int k4 = 0; k4 < F_INP / 4; k4++) {
        float4 xv = xr[k4];
        acc += xv.x * w[k4 * 4 + 0] + xv.y * w[k4 * 4 + 1]
             + xv.z * w[k4 * 4 + 2] + xv.w * w[k4 * 4 + 3];
    }
    h[(size_t)node * HDIM + c] = acc;
}

// ---------------------------------------------------------------- BN stats
// stats[0..C) = sum, stats[C..2C) = sumsq  (atomicAdd; pre-zeroed)
template <int C>
__global__ void bn_stats_kernel(const float* __restrict__ x, float* __restrict__ stats, int N) {
    const int RPB = 256 / C;
    int tid = threadIdx.x;
    int c = tid % C;
    int row0 = blockIdx.x * RPB + tid / C;
    int stride = gridDim.x * RPB;
    float s = 0.f, ss = 0.f;
    for (int r = row0; r < N; r += stride) {
        float v = x[(size_t)r * C + c];
        s += v; ss += v * v;
    }
    __shared__ float ls[256], lss[256];
    ls[tid] = s; lss[tid] = ss;
    __syncthreads();
    if (tid < C) {
        for (int k = 1; k < RPB; k++) { s += ls[tid + k * C]; ss += lss[tid + k * C]; }
        atomicAdd(&stats[c], s);
        atomicAdd(&stats[C + c], ss);
    }
}

// ---------------------------------------------------------------- aggregation
// One wave per node (lane = channel). BN+ReLU fused.
// Node id is wave-uniform (readfirstlane) -> offsets/sorted/src/edge-attr-row
// loads are uniform-address -> compiler emits scalar (s_load) fetches; the
// 16-float edge-attr row lives in SGPRs. Manual software pipeline: edge ids
// fetched 2 ahead, attr row + h row 1 ahead, so latency hides under compute.
// No seg_max needed: m in [1e-7, ~8], exp cannot overflow; softmax is
// shift-invariant.
__global__ void agg_kernel(const float* __restrict__ h, const int* __restrict__ src,
                           const float* __restrict__ ea, const float* __restrict__ We,
                           const float* __restrict__ be, const float* __restrict__ tptr,
                           const float* __restrict__ stats,
                           const float* __restrict__ gamma, const float* __restrict__ beta,
                           const int* __restrict__ offsets, const int* __restrict__ sorted,
                           float* __restrict__ out, int N) {
    int tid = threadIdx.x;
    int c = tid & 63;                        // channel == lane
    float inv = 1.0f / (float)N;
    float mu  = stats[c] * inv;
    float var = stats[HDIM + c] * inv - mu * mu;
    float rs  = rsqrtf(var + 1e-5f);
    float ga  = gamma[c], bb = beta[c];
    float w[EDIM];
#pragma unroll
    for (int k = 0; k < EDIM; k++) w[k] = We[k * HDIM + c];
    float bc = be[c];
    float tval = *tptr;

    int wid = __builtin_amdgcn_readfirstlane(tid >> 6);   // wave-uniform
    int node = blockIdx.x * 4 + wid;
    if (node >= N) return;
    int beg = offsets[node], end = offsets[node + 1];     // uniform -> s_load
    int deg = end - beg;

    float denom = 0.f, num = 0.f;
    if (deg > 0) {
        // ---- prologue: edge 0 (and id of edge 1) ----
        int e0 = sorted[beg];                // uniform -> s_load
        int s0 = src[e0];                    // uniform -> s_load
        int e1, s1;
        if (deg > 1) { e1 = sorted[beg + 1]; s1 = src[e1]; }
        else         { e1 = e0;              s1 = s0; }

        float a[EDIM];
        {
            const float* ar = ea + (size_t)e0 * EDIM;    // uniform base
#pragma unroll
            for (int k = 0; k < EDIM; k++) a[k] = ar[k]; // -> s_load_dwordx16
        }
        float hv = h[(size_t)s0 * HDIM + c];             // coalesced 256B row

        // ---- steady state: compute j while fetching j+1 ----
        for (int j = 0; j < deg - 1; j++) {
            // prefetch data for edge j+1 (always valid here)
            float an[EDIM];
            {
                const float* arn = ea + (size_t)e1 * EDIM;
#pragma unroll
                for (int k = 0; k < EDIM; k++) an[k] = arn[k];
            }
            float hn = h[(size_t)s1 * HDIM + c];
            // prefetch id for edge j+2 (clamped, branch-free)
            int nxt = (j + 2 < deg) ? (j + 2) : (deg - 1);
            int e2 = sorted[beg + nxt];
            int s2 = src[e2];

            // compute edge j
            float acc = bc;
#pragma unroll
            for (int k = 0; k < EDIM; k++) acc += a[k] * w[k];
            float zv = fmaxf((hv - mu) * rs * ga + bb, 0.f);
            float m  = fmaxf(zv + acc, 0.f) + 1e-7f;
            float ex = __expf(m * tval);
            denom += ex;
            num   += ex * m;

            // rotate pipeline registers
#pragma unroll
            for (int k = 0; k < EDIM; k++) a[k] = an[k];
            hv = hn; e1 = e2; s1 = s2;
        }
        // ---- epilogue: last edge ----
        {
            float acc = bc;
#pragma unroll
            for (int k = 0; k < EDIM; k++) acc += a[k] * w[k];
            float zv = fmaxf((hv - mu) * rs * ga + bb, 0.f);
            float m  = fmaxf(zv + acc, 0.f) + 1e-7f;
            float ex = __expf(m * tval);
            denom += ex;
            num   += ex * m;
        }
    }
    float hvn = h[(size_t)node * HDIM + c];
    float zn = fmaxf((hvn - mu) * rs * ga + bb, 0.f);
    out[(size_t)node * HDIM + c] = num / (denom + 1e-16f) + zn;
}

// ---------------------------------------------------------------- MLP part 1
// h1 = in @ W1 + b1   (N,64)@(64,128). Register tile: 4 nodes x 4 outs/thread.
__global__ __launch_bounds__(256) void mlp1_kernel(
        const float* __restrict__ in, const float* __restrict__ W1,
        const float* __restrict__ b1, float* __restrict__ h1, int N) {
    __shared__ float sW[HDIM * 128];         // 32 KB
    __shared__ float srow[32 * 65];          // +1 pad breaks bank stride
    int tid = threadIdx.x;
    for (int i = tid; i < HDIM * 128; i += 256) sW[i] = W1[i];
    int base = blockIdx.x * 32;
    for (int i = tid; i < 32 * HDIM; i += 256) {
        int r = i >> 6, cc = i & 63;
        int node = base + r;
        srow[r * 65 + cc] = (node < N) ? in[(size_t)node * HDIM + cc] : 0.f;
    }
    __syncthreads();
    int tx = tid & 31;                       // outputs 4*tx .. 4*tx+3
    int ty = tid >> 5;                       // nodes ty*4 .. ty*4+3
    float acc[4][4];
    float b0 = b1[4 * tx], bb1 = b1[4 * tx + 1], b2v = b1[4 * tx + 2], b3 = b1[4 * tx + 3];
#pragma unroll
    for (int j = 0; j < 4; j++) { acc[j][0] = b0; acc[j][1] = bb1; acc[j][2] = b2v; acc[j][3] = b3; }
#pragma unroll 8
    for (int k = 0; k < HDIM; k++) {
        float4 wv = *(const float4*)&sW[k * 128 + 4 * tx];
        float r0 = srow[(ty * 4 + 0) * 65 + k];
        float r1 = srow[(ty * 4 + 1) * 65 + k];
        float r2 = srow[(ty * 4 + 2) * 65 + k];
        float r3 = srow[(ty * 4 + 3) * 65 + k];
        acc[0][0] += r0 * wv.x; acc[0][1] += r0 * wv.y; acc[0][2] += r0 * wv.z; acc[0][3] += r0 * wv.w;
        acc[1][0] += r1 * wv.x; acc[1][1] += r1 * wv.y; acc[1][2] += r1 * wv.z; acc[1][3] += r1 * wv.w;
        acc[2][0] += r2 * wv.x; acc[2][1] += r2 * wv.y; acc[2][2] += r2 * wv.z; acc[2][3] += r2 * wv.w;
        acc[3][0] += r3 * wv.x; acc[3][1] += r3 * wv.y; acc[3][2] += r3 * wv.z; acc[3][3] += r3 * wv.w;
    }
#pragma unroll
    for (int j = 0; j < 4; j++) {
        int node = base + ty * 4 + j;
        if (node < N)
            *(float4*)&h1[(size_t)node * 128 + 4 * tx] =
                make_float4(acc[j][0], acc[j][1], acc[j][2], acc[j][3]);
    }
}

// ---------------------------------------------------------------- MLP part 2
// h += relu(BN(h1)) @ W2 + b2   (N,128)@(128,64). 2 nodes x 4 outs/thread.
__global__ __launch_bounds__(256) void mlp2_kernel(
        const float* __restrict__ h1, const float* __restrict__ stats,
        const float* __restrict__ mg, const float* __restrict__ mb,
        const float* __restrict__ W2, const float* __restrict__ b2,
        float* __restrict__ h, int N) {
    __shared__ float sW[128 * HDIM];         // 32 KB
    __shared__ float sact[32 * 129];         // 16.5 KB, +1 pad
    __shared__ float sbn[4 * 128];           // mu, rs, gamma, beta
    int tid = threadIdx.x;
    for (int i = tid; i < 128 * HDIM; i += 256) sW[i] = W2[i];
    if (tid < 128) {
        float inv = 1.0f / (float)N;
        float mu  = stats[tid] * inv;
        float var = stats[128 + tid] * inv - mu * mu;
        sbn[tid]       = mu;
        sbn[128 + tid] = rsqrtf(var + 1e-5f);
        sbn[256 + tid] = mg[tid];
        sbn[384 + tid] = mb[tid];
    }
    __syncthreads();
    int base = blockIdx.x * 32;
    for (int i = tid; i < 32 * 128; i += 256) {
        int r = i >> 7, o = i & 127;
        int node = base + r;
        float v = 0.f;
        if (node < N) {
            v = h1[(size_t)node * 128 + o];
            v = fmaxf((v - sbn[o]) * sbn[128 + o] * sbn[256 + o] + sbn[384 + o], 0.f);
        }
        sact[r * 129 + o] = v;
    }
    __syncthreads();
    int tx = tid & 15;                       // outputs 4*tx .. 4*tx+3
    int ty = tid >> 4;                       // nodes ty*2, ty*2+1
    float acc[2][4];
    float b0 = b2[4 * tx], bb1 = b2[4 * tx + 1], b2v = b2[4 * tx + 2], b3 = b2[4 * tx + 3];
    acc[0][0] = b0; acc[0][1] = bb1; acc[0][2] = b2v; acc[0][3] = b3;
    acc[1][0] = b0; acc[1][1] = bb1; acc[1][2] = b2v; acc[1][3] = b3;
#pragma unroll 8
    for (int k = 0; k < 128; k++) {
        float4 wv = *(const float4*)&sW[k * HDIM + 4 * tx];
        float r0 = sact[(ty * 2 + 0) * 129 + k];
        float r1 = sact[(ty * 2 + 1) * 129 + k];
        acc[0][0] += r0 * wv.x; acc[0][1] += r0 * wv.y; acc[0][2] += r0 * wv.z; acc[0][3] += r0 * wv.w;
        acc[1][0] += r1 * wv.x; acc[1][1] += r1 * wv.y; acc[1][2] += r1 * wv.z; acc[1][3] += r1 * wv.w;
    }
#pragma unroll
    for (int j = 0; j < 2; j++) {
        int node = base + ty * 2 + j;
        if (node < N) {
            float4* p = (float4*)&h[(size_t)node * HDIM + 4 * tx];
            float4 old = *p;
            *p = make_float4(old.x + acc[j][0], old.y + acc[j][1],
                             old.z + acc[j][2], old.w + acc[j][3]);
        }
    }
}

// ---------------------------------------------------------------- pool + head
__global__ void pool_out_kernel(const float* __restrict__ h, const int* __restrict__ gstart,
                                const float* __restrict__ Wo, const float* __restrict__ bo,
                                float* __restrict__ out, int N) {
    __shared__ float sp[HDIM];
    __shared__ float red[256];
    __shared__ float sW[HDIM * COUT];
    int g = blockIdx.x;
    int tid = threadIdx.x;
    for (int i = tid; i < HDIM * COUT; i += 256) sW[i] = Wo[i];
    int beg = gstart[g], end = gstart[g + 1];
    int c = tid & 63, r0 = tid >> 6;
    float s = 0.f;
    for (int r = beg + r0; r < end; r += 4) s += h[(size_t)r * HDIM + c];
    red[tid] = s;
    __syncthreads();
    if (tid < HDIM) {
        s = red[tid] + red[tid + 64] + red[tid + 128] + red[tid + 192];
        float cnt = (float)(end - beg);
        float pooled = s / fmaxf(cnt, 1.0f);
        sp[tid] = fmaxf(pooled, 0.0f);
    }
    __syncthreads();
    if (tid < COUT) {
        float acc = bo[tid];
#pragma unroll
        for (int k = 0; k < HDIM; k++) acc += sp[k] * sW[k * COUT + tid];
        out[g * COUT + tid] = acc;
    }
}

// ================================================================ launch
extern "C" void kernel_launch(void* const* d_in, const int* in_sizes, int n_in,
                              void* d_out, int out_size, void* d_ws, size_t ws_size,
                              hipStream_t stream) {
    (void)in_sizes; (void)n_in; (void)out_size; (void)ws_size;
    const float* x          = (const float*)d_in[0];
    const int*   eidx       = (const int*)  d_in[1];
    const float* eattr      = (const float*)d_in[2];
    const int*   batch      = (const int*)  d_in[3];
    const float* lin_in_w   = (const float*)d_in[4];
    const float* lin_in_b   = (const float*)d_in[5];
    const float* norm_gamma = (const float*)d_in[6];
    const float* norm_beta  = (const float*)d_in[7];
    const float* edge_w     = (const float*)d_in[8];
    const float* edge_b     = (const float*)d_in[9];
    const float* tparam     = (const float*)d_in[10];
    const float* mlp_w1     = (const float*)d_in[11];
    const float* mlp_b1     = (const float*)d_in[12];
    const float* mlp_gamma  = (const float*)d_in[13];
    const float* mlp_beta   = (const float*)d_in[14];
    const float* mlp_w2     = (const float*)d_in[15];
    const float* mlp_b2     = (const float*)d_in[16];
    const float* lin_out_w  = (const float*)d_in[17];
    const float* lin_out_b  = (const float*)d_in[18];
    float* out = (float*)d_out;

    const int* src = eidx;                   // edge_index[0]
    const int* dst = eidx + N_EDGES;         // edge_index[1]

    char* ws = (char*)d_ws;
    size_t off = 0;
    auto alloc = [&](size_t bytes) -> char* {
        char* p = ws + off;
        off = (off + bytes + 255) & ~(size_t)255;
        return p;
    };
    // zero-init region first (one memset covers histogram + all BN stats)
    int*   cnt     = (int*)  alloc((size_t)N_NODES * 4);
    float* statsA0 = (float*)alloc(128 * 4);
    float* statsB0 = (float*)alloc(256 * 4);
    float* statsA1 = (float*)alloc(128 * 4);
    float* statsB1 = (float*)alloc(256 * 4);
    size_t zero_bytes = off;
    int*   bsum    = (int*)  alloc(256 * 4);
    int*   offsets = (int*)  alloc((size_t)(N_NODES + 1) * 4);
    int*   cursor  = (int*)  alloc((size_t)N_NODES * 4);
    int*   sorted  = (int*)  alloc((size_t)N_EDGES * 4);
    int*   gstart  = (int*)  alloc((size_t)(NGRAPH + 1) * 4);
    float* h       = (float*)alloc((size_t)N_NODES * HDIM * 4);
    float* ob      = (float*)alloc((size_t)N_NODES * HDIM * 4);
    float* h1      = (float*)alloc((size_t)N_NODES * 2 * HDIM * 4);

    hipMemsetAsync(d_ws, 0, zero_bytes, stream);

    const int NB = (N_NODES + 255) / 256;    // 196 blocks
    hist_kernel      <<<(N_EDGES + 255) / 256, 256, 0, stream>>>(dst, cnt, N_EDGES);
    scan_part_kernel <<<NB, 256, 0, stream>>>(cnt, bsum, N_NODES);
    scan_top_kernel  <<<1, 256, 0, stream>>>(bsum, NB);
    scan_apply_kernel<<<NB, 256, 0, stream>>>(cnt, bsum, offsets, cursor, N_NODES);
    scatter_kernel   <<<(N_EDGES + 255) / 256, 256, 0, stream>>>(dst, cursor, sorted, N_EDGES);
    gstart_kernel    <<<NB, 256, 0, stream>>>(batch, gstart, N_NODES, NGRAPH);
    lin_in_kernel    <<<(N_NODES + 3) / 4, 256, 0, stream>>>(x, lin_in_w, lin_in_b, h, N_NODES);

    float* statsA[2] = { statsA0, statsA1 };
    float* statsB[2] = { statsB0, statsB1 };
    for (int l = 0; l < 2; l++) {
        bn_stats_kernel<64><<<256, 256, 0, stream>>>(h, statsA[l], N_NODES);
        agg_kernel<<<(N_NODES + 3) / 4, 256, 0, stream>>>(
            h, src, eattr, edge_w + (size_t)l * EDIM * HDIM, edge_b + l * HDIM,
            tparam + l, statsA[l], norm_gamma + l * HDIM, norm_beta + l * HDIM,
            offsets, sorted, ob, N_NODES);
        mlp1_kernel<<<(N_NODES + 31) / 32, 256, 0, stream>>>(
            ob, mlp_w1 + (size_t)l * HDIM * 2 * HDIM, mlp_b1 + l * 2 * HDIM, h1, N_NODES);
        bn_stats_kernel<128><<<256, 256, 0, stream>>>(h1, statsB[l], N_NODES);
        mlp2_kernel<<<(N_NODES + 31) / 32, 256, 0, stream>>>(
            h1, statsB[l], mlp_gamma + l * 2 * HDIM, mlp_beta + l * 2 * HDIM,
            mlp_w2 + (size_t)l * 2 * HDIM * HDIM, mlp_b2 + l * HDIM, h, N_NODES);
    }
    pool_out_kernel<<<NGRAPH, 256, 0, stream>>>(h, gstart, lin_out_w, lin_out_b, out, N_NODES);
}